// Round 4
// baseline (190.658 us; speedup 1.0000x reference)
//
#include <hip/hip_runtime.h>
#include <math.h>

typedef float  f32x4  __attribute__((ext_vector_type(4)));
typedef __bf16 bf16x8 __attribute__((ext_vector_type(8)));

#define HP_     160
#define PITCH_  (HP_*64)           // 10240 elems per padded row
#define BPITCH_ (HP_*HP_*64)       // 1638400 elems per batch

// ws layout (bytes):
//   xp   : [8][160][160][64] bf16 = 26214400  (zero halo of 16 px)
//   offs : [8][128][128][18] f32  =  9437184
//   wtb  : [9][64][64] bf16 linear =  73728
//   owt  : [9][32][64] bf16 linear =  36864   (rows 18..31 zero)
#define XP_BYTES   26214400
#define OFFS_BYTES 9437184
#define WTB_BYTES  73728

// ---------------------------------------------------------------------------
// k_prep: [0,2048) NCHW f32 -> padded NHWC bf16 ; [2048,4352) halo zero ;
//         [4352,4496) weight transpose+cast (linear layouts)
// ---------------------------------------------------------------------------
__global__ __launch_bounds__(256) void k_prep(const float* __restrict__ x,
                                              const float* __restrict__ w,
                                              const float* __restrict__ ow,
                                              __bf16* __restrict__ xp,
                                              __bf16* __restrict__ wtb,
                                              __bf16* __restrict__ owt) {
    int gid = blockIdx.x, tid = threadIdx.x;
    if (gid < 2048) {
        __shared__ float tile[64][65];
        int w0 = (gid & 1) * 64, h = (gid >> 1) & 127, b = gid >> 8;
        int lw = tid & 63, cq4 = tid >> 6;
        const float* xb = x + ((size_t)b * 64) * 16384 + (size_t)h * 128;
        #pragma unroll
        for (int it = 0; it < 16; ++it) {
            int c = it * 4 + cq4;
            tile[c][lw] = xb[(size_t)c * 16384 + w0 + lw];
        }
        __syncthreads();
        int p = tid >> 2, q = tid & 3;
        bf16x8 v0, v1;
        #pragma unroll
        for (int j = 0; j < 8; ++j) {
            v0[j] = (__bf16)tile[q * 16 + j][p];
            v1[j] = (__bf16)tile[q * 16 + 8 + j][p];
        }
        __bf16* dst = xp + (size_t)b * BPITCH_ + (size_t)(h + 16) * PITCH_
                         + (size_t)(w0 + p + 16) * 64 + q * 16;
        *(bf16x8*)dst = v0;
        *(bf16x8*)(dst + 8) = v1;
    } else if (gid < 4352) {
        int i = (gid - 2048) * 256 + tid;
        int b, y, xc, cc;
        if (i < 327680) {             // 32 full rows (top16+bottom16) x 160 px
            b = i / 40960; int r = i % 40960;
            int row = r / 1280; y = row < 16 ? row : row + 128;
            int xi = r % 1280; xc = xi >> 3; cc = (xi & 7) * 8;
        } else {                      // side cols: rows [16,144) x 32 px
            int j = i - 327680;
            b = j / 32768; int r = j % 32768;
            y = 16 + (r >> 8);
            int xi = r & 255; int xcol = xi >> 3;
            xc = xcol < 16 ? xcol : xcol + 128; cc = (xi & 7) * 8;
        }
        bf16x8 z;
        #pragma unroll
        for (int j = 0; j < 8; ++j) z[j] = (__bf16)0.f;
        *(bf16x8*)(xp + (size_t)b * BPITCH_ + (size_t)y * PITCH_ + (size_t)xc * 64 + cc) = z;
    } else {
        int i = (gid - 4352) * 256 + tid;
        if (i < 36864) {   // wtb[k][o][c] = w[o][c][k]
            int c = i & 63, o = (i >> 6) & 63, k = i >> 12;
            wtb[i] = (__bf16)w[(o * 64 + c) * 9 + k];
        }
        if (i < 18432) {   // owt[k][o][c] = off_w[o][c][k], o>=18 -> 0
            int c = i & 63, o = (i >> 6) & 31, k = i >> 11;
            owt[i] = (o < 18) ? (__bf16)ow[(o * 64 + c) * 9 + k] : (__bf16)0.f;
        }
    }
}

// ---------------------------------------------------------------------------
// k_offconv: zero-LDS, zero-barrier offset conv via MFMA.
// Wave owns 16 px (all 32 padded outputs). B-frags straight from padded x,
// A-frags straight from owt (L1/L2-resident). + bias + clip.
// ---------------------------------------------------------------------------
__global__ __launch_bounds__(256, 4) void k_offconv(const __bf16* __restrict__ xp,
                                                    const __bf16* __restrict__ owt,
                                                    const float* __restrict__ off_b,
                                                    float* __restrict__ offs) {
    int gid = blockIdx.x, tid = threadIdx.x;
    int w0 = (gid & 1) * 64, h = (gid >> 1) & 127, b = gid >> 8;
    int lane = tid & 63, wv = tid >> 6, l15 = lane & 15, lg = lane >> 4;
    int px = wv * 16 + l15;

    f32x4 acc0, acc1;
    #pragma unroll
    for (int r = 0; r < 4; ++r) {
        int o = lg * 4 + r;
        acc0[r] = (o < 18) ? off_b[o] : 0.f;
        acc1[r] = (o + 16 < 18) ? off_b[o + 16] : 0.f;
    }

    const __bf16* pb = xp + (size_t)b * BPITCH_ + (size_t)(h + 15) * PITCH_
                          + (size_t)(w0 + px + 15) * 64 + lg * 8;
    #pragma unroll
    for (int tap = 0; tap < 9; ++tap) {
        const __bf16* bs = pb + (tap / 3) * PITCH_ + (tap % 3) * 64;
        bf16x8 bv0 = *(const bf16x8*)(bs);
        bf16x8 bv1 = *(const bf16x8*)(bs + 32);
        const __bf16* ao = owt + tap * 2048 + l15 * 64 + lg * 8;
        bf16x8 a00 = *(const bf16x8*)(ao);
        bf16x8 a01 = *(const bf16x8*)(ao + 32);
        bf16x8 a10 = *(const bf16x8*)(ao + 1024);
        bf16x8 a11 = *(const bf16x8*)(ao + 1056);
        acc0 = __builtin_amdgcn_mfma_f32_16x16x32_bf16(a00, bv0, acc0, 0, 0, 0);
        acc0 = __builtin_amdgcn_mfma_f32_16x16x32_bf16(a01, bv1, acc0, 0, 0, 0);
        acc1 = __builtin_amdgcn_mfma_f32_16x16x32_bf16(a10, bv0, acc1, 0, 0, 0);
        acc1 = __builtin_amdgcn_mfma_f32_16x16x32_bf16(a11, bv1, acc1, 0, 0, 0);
    }

    float* obase = offs + (((size_t)b * 128 + h) * 128 + w0 + px) * 18;
    #pragma unroll
    for (int r = 0; r < 4; ++r) {
        int o = lg * 4 + r;
        if (o < 18) obase[o] = fminf(8.f, fmaxf(-8.f, acc0[r]));
        if (o + 16 < 18) obase[o + 16] = fminf(8.f, fmaxf(-8.f, acc1[r]));
    }
}

// ---------------------------------------------------------------------------
// k_deform: zero-LDS, zero-barrier. Wave owns 16 px x all 64 o.
// Lane samples its own pixel's 16 channels {lg*8, 32+lg*8} = exactly the
// B-fragments its wave's MFMAs need. Corner gathers prefetched 1 tap ahead
// into a register bank; A-frags read from L1-resident wtb.
// ---------------------------------------------------------------------------
struct Bank { bf16x8 c[8]; float ty, tx; };

__device__ __forceinline__ void load_bank(int k, Bank& bk, const float* my_off,
                                          float fh, float fw,
                                          const __bf16* xb_lg) {
    float2 od = *(const float2*)(my_off + 2 * k);
    float sy = od.x + (float)(k / 3) + fh;
    float sx = od.y + (float)(k % 3) + fw;
    float yf = floorf(sy), xf = floorf(sx);
    bk.ty = sy - yf; bk.tx = sx - xf;
    int yi = (int)yf, xi = (int)xf;
    const __bf16* s0 = xb_lg + (yi * HP_ + xi) * 64;
    const __bf16* s1 = s0 + PITCH_;
    bk.c[0] = *(const bf16x8*)(s0);          // (y0,x0) ch lg*8
    bk.c[1] = *(const bf16x8*)(s0 + 32);     // (y0,x0) ch 32+lg*8
    bk.c[2] = *(const bf16x8*)(s0 + 64);     // (y0,x1)
    bk.c[3] = *(const bf16x8*)(s0 + 96);
    bk.c[4] = *(const bf16x8*)(s1);          // (y1,x0)
    bk.c[5] = *(const bf16x8*)(s1 + 32);
    bk.c[6] = *(const bf16x8*)(s1 + 64);     // (y1,x1)
    bk.c[7] = *(const bf16x8*)(s1 + 96);
}

__device__ __forceinline__ void interp(const Bank& bk, bf16x8& b0, bf16x8& b1) {
    float ty = bk.ty, tx = bk.tx;
    float w00 = (1.f - ty) * (1.f - tx), w01 = (1.f - ty) * tx;
    float w10 = ty * (1.f - tx),         w11 = ty * tx;
    #pragma unroll
    for (int j = 0; j < 8; ++j) {
        float r0 = w00 * (float)bk.c[0][j] + w01 * (float)bk.c[2][j]
                 + w10 * (float)bk.c[4][j] + w11 * (float)bk.c[6][j];
        float r1 = w00 * (float)bk.c[1][j] + w01 * (float)bk.c[3][j]
                 + w10 * (float)bk.c[5][j] + w11 * (float)bk.c[7][j];
        b0[j] = (__bf16)r0;
        b1[j] = (__bf16)r1;
    }
}

__global__ __launch_bounds__(256, 3) void k_deform(const __bf16* __restrict__ xp,
                                                   const float* __restrict__ offs,
                                                   const __bf16* __restrict__ wtb,
                                                   float* __restrict__ out) {
    int gid = blockIdx.x, tid = threadIdx.x;
    int w0 = (gid & 1) * 64, h = (gid >> 1) & 127, b = gid >> 8;
    int lane = tid & 63, wv = tid >> 6, l15 = lane & 15, lg = lane >> 4;
    int px = wv * 16 + l15;

    const float* my_off = offs + (((size_t)b * 128 + h) * 128 + w0 + px) * 18;
    const __bf16* xb_lg = xp + (size_t)b * BPITCH_ + lg * 8;
    float fh = (float)(h + 15);        // base_y + pad16: h-1+16
    float fw = (float)(w0 + px + 15);  // base_x + pad16

    f32x4 acc[4];
    #pragma unroll
    for (int mi = 0; mi < 4; ++mi)
        #pragma unroll
        for (int r = 0; r < 4; ++r) acc[mi][r] = 0.f;

    Bank bank[2];
    load_bank(0, bank[0], my_off, fh, fw, xb_lg);

    #pragma unroll
    for (int k = 0; k < 9; ++k) {
        if (k < 8) load_bank(k + 1, bank[(k + 1) & 1], my_off, fh, fw, xb_lg);
        bf16x8 b0, b1;
        interp(bank[k & 1], b0, b1);
        const __bf16* wa  = wtb + k * 4096 + l15 * 64 + lg * 8;
        const __bf16* wa2 = wa + 2048;
        bf16x8 a00 = *(const bf16x8*)(wa);
        bf16x8 a01 = *(const bf16x8*)(wa + 32);
        bf16x8 a10 = *(const bf16x8*)(wa + 1024);
        bf16x8 a11 = *(const bf16x8*)(wa + 1056);
        bf16x8 a20 = *(const bf16x8*)(wa2);
        bf16x8 a21 = *(const bf16x8*)(wa2 + 32);
        bf16x8 a30 = *(const bf16x8*)(wa2 + 1024);
        bf16x8 a31 = *(const bf16x8*)(wa2 + 1056);
        acc[0] = __builtin_amdgcn_mfma_f32_16x16x32_bf16(a00, b0, acc[0], 0, 0, 0);
        acc[0] = __builtin_amdgcn_mfma_f32_16x16x32_bf16(a01, b1, acc[0], 0, 0, 0);
        acc[1] = __builtin_amdgcn_mfma_f32_16x16x32_bf16(a10, b0, acc[1], 0, 0, 0);
        acc[1] = __builtin_amdgcn_mfma_f32_16x16x32_bf16(a11, b1, acc[1], 0, 0, 0);
        acc[2] = __builtin_amdgcn_mfma_f32_16x16x32_bf16(a20, b0, acc[2], 0, 0, 0);
        acc[2] = __builtin_amdgcn_mfma_f32_16x16x32_bf16(a21, b1, acc[2], 0, 0, 0);
        acc[3] = __builtin_amdgcn_mfma_f32_16x16x32_bf16(a30, b0, acc[3], 0, 0, 0);
        acc[3] = __builtin_amdgcn_mfma_f32_16x16x32_bf16(a31, b1, acc[3], 0, 0, 0);
    }

    // epilogue: out[b][o][h][w];  o = mi*16 + lg*4 + r, col px = l15-based
    #pragma unroll
    for (int mi = 0; mi < 4; ++mi) {
        float* ob = out + ((size_t)b * 64 + mi * 16 + lg * 4) * 16384
                        + (size_t)h * 128 + w0 + px;
        ob[0]         = acc[mi][0];
        ob[16384]     = acc[mi][1];
        ob[32768]     = acc[mi][2];
        ob[49152]     = acc[mi][3];
    }
}

// ---------------------------------------------------------------------------
extern "C" void kernel_launch(void* const* d_in, const int* in_sizes, int n_in,
                              void* d_out, int out_size, void* d_ws, size_t ws_size,
                              hipStream_t stream) {
    const float* x      = (const float*)d_in[0];
    const float* weight = (const float*)d_in[1];
    const float* off_w  = (const float*)d_in[2];
    const float* off_b  = (const float*)d_in[3];
    float* out = (float*)d_out;

    char* ws = (char*)d_ws;
    __bf16* xp  = (__bf16*)ws;
    float*  offs = (float*)(ws + XP_BYTES);
    __bf16* wtb = (__bf16*)(ws + XP_BYTES + OFFS_BYTES);
    __bf16* owt = (__bf16*)(ws + XP_BYTES + OFFS_BYTES + WTB_BYTES);

    k_prep<<<4496, 256, 0, stream>>>(x, weight, off_w, xp, wtb, owt);
    k_offconv<<<2048, 256, 0, stream>>>(xp, owt, off_b, offs);
    k_deform<<<2048, 256, 0, stream>>>(xp, offs, wtb, out);
}

// Round 5
// 107.865 us; speedup vs baseline: 1.7676x; 1.7676x over previous
//
#include <hip/hip_runtime.h>
#include <math.h>

typedef float  f32x4  __attribute__((ext_vector_type(4)));
typedef __bf16 bf16x8 __attribute__((ext_vector_type(8)));

#define HP_     160
#define PITCH_  (HP_*64)           // 10240 elems per padded row
#define BPITCH_ (HP_*HP_*64)       // 1638400 elems per batch

// swizzled row: 128B rows, XOR byte-bits 4..6 with row&7 (T2/G4)
#define SWZ(row, cb) ((row)*128 + ((cb) ^ (((row)&7)<<4)))

// ws layout (bytes):
//   xp   : [8][160][160][64] bf16 = 26214400  (zero halo of 16 px)
//   offs : [8][128][128][18] f32  =  9437184
//   wtb  : [9][64][64] bf16 PRE-SWIZZLED =  73728
//   owt  : [9][32][64] bf16 PRE-SWIZZLED =  36864  (rows 18..31 zero)
#define XP_BYTES   26214400
#define OFFS_BYTES 9437184
#define WTB_BYTES  73728

__device__ __forceinline__ void gl_lds16(const void* g, void* l) {
    __builtin_amdgcn_global_load_lds(
        (const __attribute__((address_space(1))) void*)g,
        (__attribute__((address_space(3))) void*)l, 16, 0, 0);
}

// ---------------------------------------------------------------------------
// k_prep: [0,2048) NCHW f32 -> padded NHWC bf16 (XCD-remapped);
//         [2048,4352) halo zero ; [4352,4496) weight transpose+cast+swizzle
// ---------------------------------------------------------------------------
__global__ __launch_bounds__(256) void k_prep(const float* __restrict__ x,
                                              const float* __restrict__ w,
                                              const float* __restrict__ ow,
                                              __bf16* __restrict__ xp,
                                              __bf16* __restrict__ wtb,
                                              __bf16* __restrict__ owt) {
    int gid = blockIdx.x, tid = threadIdx.x;
    if (gid < 2048) {
        __shared__ float tile[64][65];
        int b = gid & 7, rem = gid >> 3;
        int w0 = (rem & 1) * 64, h = (rem >> 1) & 127;
        int lw = tid & 63, cq4 = tid >> 6;
        const float* xb = x + ((size_t)b * 64) * 16384 + (size_t)h * 128;
        #pragma unroll
        for (int it = 0; it < 16; ++it) {
            int c = it * 4 + cq4;
            tile[c][lw] = xb[(size_t)c * 16384 + w0 + lw];
        }
        __syncthreads();
        int p = tid >> 2, q = tid & 3;
        bf16x8 v0, v1;
        #pragma unroll
        for (int j = 0; j < 8; ++j) {
            v0[j] = (__bf16)tile[q * 16 + j][p];
            v1[j] = (__bf16)tile[q * 16 + 8 + j][p];
        }
        __bf16* dst = xp + (size_t)b * BPITCH_ + (size_t)(h + 16) * PITCH_
                         + (size_t)(w0 + p + 16) * 64 + q * 16;
        *(bf16x8*)dst = v0;
        *(bf16x8*)(dst + 8) = v1;
    } else if (gid < 4352) {
        int i = (gid - 2048) * 256 + tid;
        int b, y, xc, cc;
        if (i < 327680) {             // 32 full rows (top16+bottom16) x 160 px
            b = i / 40960; int r = i % 40960;
            int row = r / 1280; y = row < 16 ? row : row + 128;
            int xi = r % 1280; xc = xi >> 3; cc = (xi & 7) * 8;
        } else {                      // side cols: rows [16,144) x 32 px
            int j = i - 327680;
            b = j / 32768; int r = j % 32768;
            y = 16 + (r >> 8);
            int xi = r & 255; int xcol = xi >> 3;
            xc = xcol < 16 ? xcol : xcol + 128; cc = (xi & 7) * 8;
        }
        bf16x8 z;
        #pragma unroll
        for (int j = 0; j < 8; ++j) z[j] = (__bf16)0.f;
        *(bf16x8*)(xp + (size_t)b * BPITCH_ + (size_t)y * PITCH_ + (size_t)xc * 64 + cc) = z;
    } else {
        int i = (gid - 4352) * 256 + tid;
        if (i < 36864) {   // wtb[k][o][c^((o&7)<<3)] = w[o][c][k]
            int c = i & 63, o = (i >> 6) & 63, k = i >> 12;
            wtb[(k << 12) + (o << 6) + (c ^ ((o & 7) << 3))] = (__bf16)w[(o * 64 + c) * 9 + k];
        }
        if (i < 18432) {   // owt[k][o][c^] = off_w[o][c][k], o>=18 -> 0
            int c = i & 63, o = (i >> 6) & 31, k = i >> 11;
            owt[(k << 11) + (o << 6) + (c ^ ((o & 7) << 3))] =
                (o < 18) ? (__bf16)ow[(o * 64 + c) * 9 + k] : (__bf16)0.f;
        }
    }
}

// ---------------------------------------------------------------------------
// k_offconv: round-3 proven version + XCD remap. owt staged once via linear
// gl_lds (source pre-swizzled), branchless B-frags from padded x, bias+clip.
// ---------------------------------------------------------------------------
__global__ __launch_bounds__(256) void k_offconv(const __bf16* __restrict__ xp,
                                                 const __bf16* __restrict__ owt,
                                                 const float* __restrict__ off_b,
                                                 float* __restrict__ offs) {
    __shared__ alignas(16) short wlo[9 * 32 * 64];   // 36864 B
    int gid = blockIdx.x, tid = threadIdx.x;
    int b = gid & 7, rem = gid >> 3;
    int w0 = (rem & 1) * 64, h = (rem >> 1) & 127;
    int lane = tid & 63, wv = tid >> 6, l15 = lane & 15, lg = lane >> 4;

    {
        const char* s = (const char*)owt + wv * 9216 + lane * 16;
        char* d = (char*)wlo + wv * 9216;
        #pragma unroll
        for (int it = 0; it < 9; ++it) gl_lds16(s + it * 1024, d + it * 1024);
    }

    f32x4 acc0, acc1;
    #pragma unroll
    for (int r = 0; r < 4; ++r) {
        int o = lg * 4 + r;
        acc0[r] = (o < 18) ? off_b[o] : 0.f;
        acc1[r] = (o + 16 < 18) ? off_b[o + 16] : 0.f;
    }
    __syncthreads();

    int px = wv * 16 + l15;
    const __bf16* pbase = xp + (size_t)b * BPITCH_ + (size_t)(h + 15) * PITCH_
                             + (size_t)(w0 + px + 15) * 64 + lg * 8;
    #pragma unroll
    for (int tap = 0; tap < 9; ++tap) {
        const __bf16* bsrc = pbase + (tap / 3) * PITCH_ + (tap % 3) * 64;
        const char* wb = (const char*)wlo + tap * 4096;
        #pragma unroll
        for (int ks = 0; ks < 2; ++ks) {
            int cb = ks * 64 + lg * 16;
            bf16x8 a0 = *(const bf16x8*)(wb + SWZ(l15, cb));
            bf16x8 a1 = *(const bf16x8*)(wb + SWZ(16 + l15, cb));
            bf16x8 bv = *(const bf16x8*)(bsrc + ks * 32);
            acc0 = __builtin_amdgcn_mfma_f32_16x16x32_bf16(a0, bv, acc0, 0, 0, 0);
            acc1 = __builtin_amdgcn_mfma_f32_16x16x32_bf16(a1, bv, acc1, 0, 0, 0);
        }
    }
    float* obase = offs + (((size_t)b * 128 + h) * 128 + w0 + px) * 18;
    #pragma unroll
    for (int r = 0; r < 4; ++r) {
        int o = lg * 4 + r;
        if (o < 18) obase[o] = fminf(8.f, fmaxf(-8.f, acc0[r]));
        if (o + 16 < 18) obase[o + 16] = fminf(8.f, fmaxf(-8.f, acc1[r]));
    }
}

// ---------------------------------------------------------------------------
// k_deform: wave owns 16 px x all 64 o; lane's bilinear samples ARE its
// B-fragments (no sample LDS, no per-tap barriers). Weights taps 0..7 staged
// once in 64KB LDS (ds_read = lgkmcnt, decoupled from gather vmcnt); tap 8
// read from global with the same SWZ address math. Corner gathers prefetched
// 3 taps deep; offsets preloaded to regs so vmcnt queue = corners only.
// ---------------------------------------------------------------------------
struct Bank { bf16x8 c[8]; float ty, tx; };

__device__ __forceinline__ void load_bank(float2 od, int k, Bank& bk,
                                          float fh, float fw,
                                          const __bf16* xb_lg) {
    float sy = od.x + (float)(k / 3) + fh;
    float sx = od.y + (float)(k % 3) + fw;
    float yf = floorf(sy), xf = floorf(sx);
    bk.ty = sy - yf; bk.tx = sx - xf;
    int yi = (int)yf, xi = (int)xf;
    const __bf16* s0 = xb_lg + (yi * HP_ + xi) * 64;
    const __bf16* s1 = s0 + PITCH_;
    bk.c[0] = *(const bf16x8*)(s0);          // (y0,x0) ch lg*8
    bk.c[1] = *(const bf16x8*)(s0 + 32);     // (y0,x0) ch 32+lg*8
    bk.c[2] = *(const bf16x8*)(s0 + 64);     // (y0,x1)
    bk.c[3] = *(const bf16x8*)(s0 + 96);
    bk.c[4] = *(const bf16x8*)(s1);          // (y1,x0)
    bk.c[5] = *(const bf16x8*)(s1 + 32);
    bk.c[6] = *(const bf16x8*)(s1 + 64);     // (y1,x1)
    bk.c[7] = *(const bf16x8*)(s1 + 96);
}

__device__ __forceinline__ void interp(const Bank& bk, bf16x8& b0, bf16x8& b1) {
    float ty = bk.ty, tx = bk.tx;
    float w00 = (1.f - ty) * (1.f - tx), w01 = (1.f - ty) * tx;
    float w10 = ty * (1.f - tx),         w11 = ty * tx;
    #pragma unroll
    for (int j = 0; j < 8; ++j) {
        float r0 = w00 * (float)bk.c[0][j] + w01 * (float)bk.c[2][j]
                 + w10 * (float)bk.c[4][j] + w11 * (float)bk.c[6][j];
        float r1 = w00 * (float)bk.c[1][j] + w01 * (float)bk.c[3][j]
                 + w10 * (float)bk.c[5][j] + w11 * (float)bk.c[7][j];
        b0[j] = (__bf16)r0;
        b1[j] = (__bf16)r1;
    }
}

__global__ __launch_bounds__(256, 2) void k_deform(const __bf16* __restrict__ xp,
                                                   const float* __restrict__ offs,
                                                   const __bf16* __restrict__ wtb,
                                                   float* __restrict__ out) {
    __shared__ alignas(16) short wl[8 * 4096];   // 64 KB: taps 0..7, swizzled

    int gid = blockIdx.x, tid = threadIdx.x;
    int b = gid & 7, rem = gid >> 3;             // XCD q <- batch q (L2-fit)
    int w0 = (rem & 1) * 64, h = (rem >> 1) & 127;
    int lane = tid & 63, wv = tid >> 6, l15 = lane & 15, lg = lane >> 4;
    int px = wv * 16 + l15;

    {   // stage taps 0..7: 64 x 1KB gl_lds, 16 per wave (linear, pre-swz src)
        const char* s = (const char*)wtb + wv * 16384 + lane * 16;
        char* d = (char*)wl + wv * 16384;
        #pragma unroll
        for (int i = 0; i < 16; ++i) gl_lds16(s + i * 1024, d + i * 1024);
    }

    // preload all 9 offset pairs -> regs (keeps vmcnt queue = corners only)
    const float* my_off = offs + (((size_t)b * 128 + h) * 128 + w0 + px) * 18;
    float2 offv[9];
    #pragma unroll
    for (int k = 0; k < 9; ++k) offv[k] = *(const float2*)(my_off + 2 * k);

    const __bf16* xb_lg = xp + (size_t)b * BPITCH_ + lg * 8;
    float fh = (float)(h + 15);        // h-1+16 (pad)
    float fw = (float)(w0 + px + 15);  // w-1+16 (pad)

    f32x4 acc[4];
    #pragma unroll
    for (int mi = 0; mi < 4; ++mi)
        #pragma unroll
        for (int r = 0; r < 4; ++r) acc[mi][r] = 0.f;

    Bank bank[3];
    load_bank(offv[0], 0, bank[0], fh, fw, xb_lg);
    load_bank(offv[1], 1, bank[1], fh, fw, xb_lg);
    load_bank(offv[2], 2, bank[2], fh, fw, xb_lg);
    __syncthreads();   // weights staged (startup drain, once)

    #pragma unroll
    for (int k = 0; k < 9; ++k) {
        bf16x8 b0, b1;
        interp(bank[k % 3], b0, b1);
        if (k < 6) load_bank(offv[k + 3], k + 3, bank[k % 3], fh, fw, xb_lg);

        bf16x8 a0, a1, a2, a3, a4, a5, a6, a7;
        if (k < 8) {
            const char* wb = (const char*)wl + k * 8192;
            a0 = *(const bf16x8*)(wb + SWZ(l15,      lg * 16));
            a1 = *(const bf16x8*)(wb + SWZ(l15,      64 + lg * 16));
            a2 = *(const bf16x8*)(wb + SWZ(16 + l15, lg * 16));
            a3 = *(const bf16x8*)(wb + SWZ(16 + l15, 64 + lg * 16));
            a4 = *(const bf16x8*)(wb + SWZ(32 + l15, lg * 16));
            a5 = *(const bf16x8*)(wb + SWZ(32 + l15, 64 + lg * 16));
            a6 = *(const bf16x8*)(wb + SWZ(48 + l15, lg * 16));
            a7 = *(const bf16x8*)(wb + SWZ(48 + l15, 64 + lg * 16));
        } else {
            const char* wg = (const char*)wtb + 8 * 8192;   // same SWZ math
            a0 = *(const bf16x8*)(wg + SWZ(l15,      lg * 16));
            a1 = *(const bf16x8*)(wg + SWZ(l15,      64 + lg * 16));
            a2 = *(const bf16x8*)(wg + SWZ(16 + l15, lg * 16));
            a3 = *(const bf16x8*)(wg + SWZ(16 + l15, 64 + lg * 16));
            a4 = *(const bf16x8*)(wg + SWZ(32 + l15, lg * 16));
            a5 = *(const bf16x8*)(wg + SWZ(32 + l15, 64 + lg * 16));
            a6 = *(const bf16x8*)(wg + SWZ(48 + l15, lg * 16));
            a7 = *(const bf16x8*)(wg + SWZ(48 + l15, 64 + lg * 16));
        }
        acc[0] = __builtin_amdgcn_mfma_f32_16x16x32_bf16(a0, b0, acc[0], 0, 0, 0);
        acc[0] = __builtin_amdgcn_mfma_f32_16x16x32_bf16(a1, b1, acc[0], 0, 0, 0);
        acc[1] = __builtin_amdgcn_mfma_f32_16x16x32_bf16(a2, b0, acc[1], 0, 0, 0);
        acc[1] = __builtin_amdgcn_mfma_f32_16x16x32_bf16(a3, b1, acc[1], 0, 0, 0);
        acc[2] = __builtin_amdgcn_mfma_f32_16x16x32_bf16(a4, b0, acc[2], 0, 0, 0);
        acc[2] = __builtin_amdgcn_mfma_f32_16x16x32_bf16(a5, b1, acc[2], 0, 0, 0);
        acc[3] = __builtin_amdgcn_mfma_f32_16x16x32_bf16(a6, b0, acc[3], 0, 0, 0);
        acc[3] = __builtin_amdgcn_mfma_f32_16x16x32_bf16(a7, b1, acc[3], 0, 0, 0);
    }

    // epilogue: out[b][o][h][w];  o = mi*16 + lg*4 + r, px col = l15-based
    #pragma unroll
    for (int mi = 0; mi < 4; ++mi) {
        float* ob = out + ((size_t)b * 64 + mi * 16 + lg * 4) * 16384
                        + (size_t)h * 128 + w0 + px;
        ob[0]     = acc[mi][0];
        ob[16384] = acc[mi][1];
        ob[32768] = acc[mi][2];
        ob[49152] = acc[mi][3];
    }
}

// ---------------------------------------------------------------------------
extern "C" void kernel_launch(void* const* d_in, const int* in_sizes, int n_in,
                              void* d_out, int out_size, void* d_ws, size_t ws_size,
                              hipStream_t stream) {
    const float* x      = (const float*)d_in[0];
    const float* weight = (const float*)d_in[1];
    const float* off_w  = (const float*)d_in[2];
    const float* off_b  = (const float*)d_in[3];
    float* out = (float*)d_out;

    char* ws = (char*)d_ws;
    __bf16* xp  = (__bf16*)ws;
    float*  offs = (float*)(ws + XP_BYTES);
    __bf16* wtb = (__bf16*)(ws + XP_BYTES + OFFS_BYTES);
    __bf16* owt = (__bf16*)(ws + XP_BYTES + OFFS_BYTES + WTB_BYTES);

    k_prep<<<4496, 256, 0, stream>>>(x, weight, off_w, xp, wtb, owt);
    k_offconv<<<2048, 256, 0, stream>>>(xp, owt, off_b, offs);
    k_deform<<<2048, 256, 0, stream>>>(xp, offs, wtb, out);
}

// Round 6
// 101.870 us; speedup vs baseline: 1.8716x; 1.0588x over previous
//
#include <hip/hip_runtime.h>
#include <math.h>

typedef float  f32x4   __attribute__((ext_vector_type(4)));
typedef __bf16 bf16x8  __attribute__((ext_vector_type(8)));
typedef __bf16 bf16x16 __attribute__((ext_vector_type(16)));

#define HP_     160
#define PITCH_  (HP_*64)           // elems per padded row
#define BPITCH_ (HP_*HP_*64)       // elems per batch

// swizzled row: 128B rows, XOR byte-bits 4..6 with row&7 (T2/G4)
#define SWZ(row, cb) ((row)*128 + ((cb) ^ (((row)&7)<<4)))

// channel permutation: n(c) = ((c>>3)&3)*16 + (c>>5)*8 + (c&7)
// -> lane lg's 16 needed channels (orig {lg*8..+7, 32+lg*8..+7}) are the
//    contiguous 32B chunk at element offset lg*16.

// ws layout (bytes):
//   xp  : [8][160][160][64] bf16 = 26214400  (zero halo, permuted channels)
//   wtb : [9][64][64] bf16 pre-swizzled+permuted = 73728
//   owt : [9][32][64] bf16 pre-swizzled+permuted = 36864 (rows 18..31 zero)
#define XP_BYTES   26214400
#define WTB_BYTES  73728

__device__ __forceinline__ void gl_lds16(const void* g, void* l) {
    __builtin_amdgcn_global_load_lds(
        (const __attribute__((address_space(1))) void*)g,
        (__attribute__((address_space(3))) void*)l, 16, 0, 0);
}

__device__ __forceinline__ float clip8(float v) {
    return fminf(8.f, fmaxf(-8.f, v));
}

// ---------------------------------------------------------------------------
// k_prep: [0,2048) NCHW f32 -> padded NHWC bf16, channels permuted;
//         [2048,4352) halo zero; [4352,4496) weights: transpose+cast+perm+swz
// ---------------------------------------------------------------------------
__global__ __launch_bounds__(256) void k_prep(const float* __restrict__ x,
                                              const float* __restrict__ w,
                                              const float* __restrict__ ow,
                                              __bf16* __restrict__ xp,
                                              __bf16* __restrict__ wtb,
                                              __bf16* __restrict__ owt) {
    int gid = blockIdx.x, tid = threadIdx.x;
    if (gid < 2048) {
        __shared__ float tile[64][65];
        int b = gid & 7, rem = gid >> 3;
        int w0 = (rem & 1) * 64, h = (rem >> 1) & 127;
        int lw = tid & 63, cq4 = tid >> 6;
        const float* xb = x + ((size_t)b * 64) * 16384 + (size_t)h * 128;
        #pragma unroll
        for (int it = 0; it < 16; ++it) {
            int c = it * 4 + cq4;
            tile[c][lw] = xb[(size_t)c * 16384 + w0 + lw];
        }
        __syncthreads();
        int p = tid >> 2, q = tid & 3;
        // n-position q*16+j <- orig c = q*8+j ; q*16+8+j <- c = 32+q*8+j
        bf16x8 v0, v1;
        #pragma unroll
        for (int j = 0; j < 8; ++j) {
            v0[j] = (__bf16)tile[q * 8 + j][p];
            v1[j] = (__bf16)tile[32 + q * 8 + j][p];
        }
        __bf16* dst = xp + (size_t)b * BPITCH_ + (size_t)(h + 16) * PITCH_
                         + (size_t)(w0 + p + 16) * 64 + q * 16;
        *(bf16x8*)dst = v0;
        *(bf16x8*)(dst + 8) = v1;
    } else if (gid < 4352) {
        int i = (gid - 2048) * 256 + tid;
        int b, y, xc, cc;
        if (i < 327680) {
            b = i / 40960; int r = i % 40960;
            int row = r / 1280; y = row < 16 ? row : row + 128;
            int xi = r % 1280; xc = xi >> 3; cc = (xi & 7) * 8;
        } else {
            int j = i - 327680;
            b = j / 32768; int r = j % 32768;
            y = 16 + (r >> 8);
            int xi = r & 255; int xcol = xi >> 3;
            xc = xcol < 16 ? xcol : xcol + 128; cc = (xi & 7) * 8;
        }
        bf16x8 z;
        #pragma unroll
        for (int j = 0; j < 8; ++j) z[j] = (__bf16)0.f;
        *(bf16x8*)(xp + (size_t)b * BPITCH_ + (size_t)y * PITCH_ + (size_t)xc * 64 + cc) = z;
    } else {
        int i = (gid - 4352) * 256 + tid;
        if (i < 36864) {
            int c = i & 63, o = (i >> 6) & 63, k = i >> 12;
            int n = ((c >> 3) & 3) * 16 + ((c >> 5) << 3) + (c & 7);
            wtb[(k << 12) + (o << 6) + (n ^ ((o & 7) << 3))] = (__bf16)w[(o * 64 + c) * 9 + k];
        }
        if (i < 18432) {
            int c = i & 63, o = (i >> 6) & 31, k = i >> 11;
            int n = ((c >> 3) & 3) * 16 + ((c >> 5) << 3) + (c & 7);
            owt[(k << 11) + (o << 6) + (n ^ ((o & 7) << 3))] =
                (o < 18) ? (__bf16)ow[(o * 64 + c) * 9 + k] : (__bf16)0.f;
        }
    }
}

// ---------------------------------------------------------------------------
// k_main: fused offset-conv + deformable conv.
// Phase 1: owt taps 0-7 in 32KB LDS slots (tap 8 from global), fixed-tap
//          MFMA conv -> clipped offsets -> offl[64][18] in LDS.
// Phase 2: deform weights taps 0-3 staged into the same slots; taps 4-7
//          rolling-refilled (raw s_barrier at ends of taps 0-6; refill R(k+4)
//          issued after barrier@k; drains proven by corner-wait vmcnt order);
//          tap 8 weights from global. Corner gathers: 4x32B chunks/lane,
//          prefetch depth 2. Lane's samples ARE its B-fragments.
// ---------------------------------------------------------------------------
struct Bank { bf16x16 c00, c01, c10, c11; float ty, tx; };

__device__ __forceinline__ void load_bank(int k, Bank& bk,
                                          const float (*offl)[18], int px,
                                          float fh, float fw,
                                          const __bf16* xb) {
    float2 od = *(const float2*)&offl[px][2 * k];
    float sy = od.x + (float)(k / 3) + fh;
    float sx = od.y + (float)(k % 3) + fw;
    float yf = floorf(sy), xf = floorf(sx);
    bk.ty = sy - yf; bk.tx = sx - xf;
    int yi = (int)yf, xi = (int)xf;
    const __bf16* s0 = xb + (yi * HP_ + xi) * 64;
    bk.c00 = *(const bf16x16*)(s0);
    bk.c01 = *(const bf16x16*)(s0 + 64);
    bk.c10 = *(const bf16x16*)(s0 + PITCH_);
    bk.c11 = *(const bf16x16*)(s0 + PITCH_ + 64);
}

__device__ __forceinline__ void interp(const Bank& bk, bf16x8& b0, bf16x8& b1) {
    float ty = bk.ty, tx = bk.tx;
    float w00 = (1.f - ty) * (1.f - tx), w01 = (1.f - ty) * tx;
    float w10 = ty * (1.f - tx),         w11 = ty * tx;
    #pragma unroll
    for (int j = 0; j < 8; ++j) {
        b0[j] = (__bf16)(w00 * (float)bk.c00[j] + w01 * (float)bk.c01[j]
                       + w10 * (float)bk.c10[j] + w11 * (float)bk.c11[j]);
        b1[j] = (__bf16)(w00 * (float)bk.c00[8 + j] + w01 * (float)bk.c01[8 + j]
                       + w10 * (float)bk.c10[8 + j] + w11 * (float)bk.c11[8 + j]);
    }
}

__global__ __launch_bounds__(256, 4) void k_main(const __bf16* __restrict__ xp,
                                                 const __bf16* __restrict__ wtb,
                                                 const __bf16* __restrict__ owt,
                                                 const float* __restrict__ off_b,
                                                 float* __restrict__ out) {
    __shared__ alignas(16) char slots[32768];   // 4 x 8KB (phase1: 8 x 4KB)
    __shared__ float offl[64][18];              // 4.6 KB

    int gid = blockIdx.x, tid = threadIdx.x;
    int b = gid & 7, rem = gid >> 3;            // XCD i <- batch i (L2 local)
    int w0 = (rem & 1) * 64, h = (rem >> 1) & 127;
    int lane = tid & 63, wv = tid >> 6, l15 = lane & 15, lg = lane >> 4;
    int px = wv * 16 + l15;

    {   // stage owt taps 0..7 (32KB linear; source pre-swizzled)
        const char* s = (const char*)owt + wv * 8192 + lane * 16;
        char* d = slots + wv * 8192;
        #pragma unroll
        for (int i = 0; i < 8; ++i) gl_lds16(s + i * 1024, d + i * 1024);
    }

    f32x4 acc0, acc1;
    #pragma unroll
    for (int r = 0; r < 4; ++r) {
        int o = lg * 4 + r;
        acc0[r] = (o < 18) ? off_b[o] : 0.f;
        acc1[r] = (o + 16 < 18) ? off_b[o + 16] : 0.f;
    }
    __syncthreads();

    // ---- phase 1: offset conv ----
    const __bf16* pbase = xp + (size_t)b * BPITCH_ + (size_t)(h + 15) * PITCH_
                             + (size_t)(w0 + px + 15) * 64 + lg * 16;
    #pragma unroll
    for (int tap = 0; tap < 9; ++tap) {
        bf16x16 bv = *(const bf16x16*)(pbase + (tap / 3) * PITCH_ + (tap % 3) * 64);
        bf16x8 b0 = __builtin_shufflevector(bv, bv, 0, 1, 2, 3, 4, 5, 6, 7);
        bf16x8 b1 = __builtin_shufflevector(bv, bv, 8, 9, 10, 11, 12, 13, 14, 15);
        bf16x8 a00, a01, a10, a11;
        if (tap < 8) {
            const char* wb = slots + tap * 4096;
            a00 = *(const bf16x8*)(wb + SWZ(l15,      lg * 32));
            a01 = *(const bf16x8*)(wb + SWZ(l15,      lg * 32 + 16));
            a10 = *(const bf16x8*)(wb + SWZ(16 + l15, lg * 32));
            a11 = *(const bf16x8*)(wb + SWZ(16 + l15, lg * 32 + 16));
        } else {
            const char* wg = (const char*)owt + 32768;
            a00 = *(const bf16x8*)(wg + SWZ(l15,      lg * 32));
            a01 = *(const bf16x8*)(wg + SWZ(l15,      lg * 32 + 16));
            a10 = *(const bf16x8*)(wg + SWZ(16 + l15, lg * 32));
            a11 = *(const bf16x8*)(wg + SWZ(16 + l15, lg * 32 + 16));
        }
        acc0 = __builtin_amdgcn_mfma_f32_16x16x32_bf16(a00, b0, acc0, 0, 0, 0);
        acc0 = __builtin_amdgcn_mfma_f32_16x16x32_bf16(a01, b1, acc0, 0, 0, 0);
        acc1 = __builtin_amdgcn_mfma_f32_16x16x32_bf16(a10, b0, acc1, 0, 0, 0);
        acc1 = __builtin_amdgcn_mfma_f32_16x16x32_bf16(a11, b1, acc1, 0, 0, 0);
    }
    #pragma unroll
    for (int r = 0; r < 4; ++r) offl[px][lg * 4 + r] = clip8(acc0[r]);
    if (lg == 0) { offl[px][16] = clip8(acc1[0]); offl[px][17] = clip8(acc1[1]); }
    __syncthreads();                             // offl ready; owt reads done

    {   // stage deform taps 0..3 into slots (32KB)
        const char* s = (const char*)wtb + wv * 8192 + lane * 16;
        char* d = slots + wv * 8192;
        #pragma unroll
        for (int i = 0; i < 8; ++i) gl_lds16(s + i * 1024, d + i * 1024);
    }
    __syncthreads();                             // drains staging (vmcnt 0)

    // ---- phase 2: deformable conv ----
    f32x4 acc[4];
    #pragma unroll
    for (int mi = 0; mi < 4; ++mi)
        #pragma unroll
        for (int r = 0; r < 4; ++r) acc[mi][r] = 0.f;

    const __bf16* xb = xp + (size_t)b * BPITCH_ + lg * 16;
    float fh = (float)(h + 15);        // h-1+16 (pad)
    float fw = (float)(w0 + px + 15);  // w-1+16 (pad)

    Bank bank0, bank1;
    load_bank(0, bank0, offl, px, fh, fw, xb);
    load_bank(1, bank1, offl, px, fh, fw, xb);

    #pragma unroll
    for (int k = 0; k < 9; ++k) {
        bf16x8 b0, b1;
        if (k & 1) interp(bank1, b0, b1); else interp(bank0, b0, b1);
        if (k < 7) {
            if (k & 1) load_bank(k + 2, bank1, offl, px, fh, fw, xb);
            else       load_bank(k + 2, bank0, offl, px, fh, fw, xb);
        }

        bf16x8 a[8];
        if (k < 8) {
            const char* wb = slots + (k & 3) * 8192;
            #pragma unroll
            for (int mi = 0; mi < 4; ++mi) {
                a[2 * mi]     = *(const bf16x8*)(wb + SWZ(mi * 16 + l15, lg * 32));
                a[2 * mi + 1] = *(const bf16x8*)(wb + SWZ(mi * 16 + l15, lg * 32 + 16));
            }
        } else {
            const char* wg = (const char*)wtb + 8 * 8192;
            #pragma unroll
            for (int mi = 0; mi < 4; ++mi) {
                a[2 * mi]     = *(const bf16x8*)(wg + SWZ(mi * 16 + l15, lg * 32));
                a[2 * mi + 1] = *(const bf16x8*)(wg + SWZ(mi * 16 + l15, lg * 32 + 16));
            }
        }
        #pragma unroll
        for (int mi = 0; mi < 4; ++mi) {
            acc[mi] = __builtin_amdgcn_mfma_f32_16x16x32_bf16(a[2 * mi],     b0, acc[mi], 0, 0, 0);
            acc[mi] = __builtin_amdgcn_mfma_f32_16x16x32_bf16(a[2 * mi + 1], b1, acc[mi], 0, 0, 0);
        }

        if (k < 7) {
            __builtin_amdgcn_s_barrier();          // raw: no vmcnt drain
            __builtin_amdgcn_sched_barrier(0);     // pin refill below barrier
            if (k < 4) {                           // refill tap k+4 -> slot k
                const char* s = (const char*)wtb + (k + 4) * 8192 + wv * 2048 + lane * 16;
                char* d = slots + (k & 3) * 8192 + wv * 2048;
                gl_lds16(s, d);
                gl_lds16(s + 1024, d + 1024);
            }
        }
    }

    // epilogue: out[b][o][h][w];  o = mi*16 + lg*4 + r, px = col
    #pragma unroll
    for (int mi = 0; mi < 4; ++mi) {
        float* ob = out + ((size_t)b * 64 + mi * 16 + lg * 4) * 16384
                        + (size_t)h * 128 + w0 + px;
        ob[0]     = acc[mi][0];
        ob[16384] = acc[mi][1];
        ob[32768] = acc[mi][2];
        ob[49152] = acc[mi][3];
    }
}

// ---------------------------------------------------------------------------
extern "C" void kernel_launch(void* const* d_in, const int* in_sizes, int n_in,
                              void* d_out, int out_size, void* d_ws, size_t ws_size,
                              hipStream_t stream) {
    const float* x      = (const float*)d_in[0];
    const float* weight = (const float*)d_in[1];
    const float* off_w  = (const float*)d_in[2];
    const float* off_b  = (const float*)d_in[3];
    float* out = (float*)d_out;

    char* ws = (char*)d_ws;
    __bf16* xp  = (__bf16*)ws;
    __bf16* wtb = (__bf16*)(ws + XP_BYTES);
    __bf16* owt = (__bf16*)(ws + XP_BYTES + WTB_BYTES);

    k_prep<<<4496, 256, 0, stream>>>(x, weight, off_w, xp, wtb, owt);
    k_main<<<2048, 256, 0, stream>>>(xp, wtb, owt, off_b, out);
}